// Round 6
// baseline (579.285 us; speedup 1.0000x reference)
//
#include <hip/hip_runtime.h>

// Chamfer distance K=1 NN, both directions, via EXACT grid-pruned search.
// N=4, P1=P2=8192, D=3, fp32. Points ~ N(0,1)^3.
//
// Exactness argument (no approximation anywhere in the OUTPUT):
//  - Every candidate pair distance uses the bitwise reference formula
//    (fp contract off):  dot = ((qx*tx)+(qy*ty))+(qz*tz);
//                        tt  = fmaf(-2, dot, sp+sq)
//    with sp/sq = ((x*x)+(y*y))+(z*z) exactly as the prep of prior rounds.
//  - Selection is lexicographic min over (tt, orig_idx): identical to
//    numpy argmin first-occurrence semantics (smallest index on ties).
//  - Ring expansion around the query's home cell stops only when
//    best < minface^2 - 5e-5, where minface = exact distance from the
//    query to the boundary of the box of explored cells, shrunk by 1e-5
//    (covers box-edge rounding ~1e-6). The 5e-5 absolute slack covers
//    worst-case catastrophic-cancellation rounding of tt vs true d2
//    (|coords| <= ~5.5 -> sp+sq <= ~60, ~6 roundings -> < 2.5e-5).
//    Unexplored true d2 >= minface^2, so unexplored tt > best strictly
//    (ties included). Points clamped into boundary cells (|coord|>4.8,
//    ~0.3 expected per run) remain correct: their true coords lie outside
//    any explored box that excludes their cell. Queries outside their
//    home cell make minface<0 -> no early break -> correct, just slower.
//  - Scatter order within a cell is atomic-nondeterministic, but the
//    explored SET and the lexicographic min are order-independent ->
//    deterministic results across runs/replays.
//
// ws layout (32-bit slots, total 524288 = 2 MB, same footprint as before):
//   [0      .. 262143]  u32 cnt[8 clouds][32768 cells]:
//                       counts (K1) -> exclusive starts (K2) ->
//                       cursors/end-pointers (K3/K4: E[c] = start[c+1])
//   [262144 .. 524287]  v4f P[65536]: sorted (x, y, z, idx_bits) AoS

typedef float v4f __attribute__((ext_vector_type(4)));

#define NC 32
#define NCELLS (NC * NC * NC)
#define GL0 -4.8f
#define GH 0.3f
#define GINVH (1.0f / 0.3f)

#define OFF_CNT 0
#define OFF_P   262144

__device__ __forceinline__ int cell1d(float v) {
#pragma clang fp contract(off)
    // (v - GL0) * GINVH : sub-then-mul, no mul+add pattern -> no fma
    // contraction possible; identical sequence in all kernels (K1/K3
    // consistency is correctness-critical for the scatter).
    int c = (int)floorf((v - GL0) * GINVH);
    return min(max(c, 0), NC - 1);
}

__global__ __launch_bounds__(256) void grid_count(const float* __restrict__ x,
                                                  const float* __restrict__ y,
                                                  unsigned int* __restrict__ cnt) {
#pragma clang fp contract(off)
    int g = blockIdx.x * 256 + threadIdx.x;   // 0..65535
    int k = g >> 13;                          // cloud = batch*2 + w
    int i = g & 8191;
    int n = k >> 1, w = k & 1;
    const float* src = w ? y : x;
    const float* p = src + (size_t)(n * 8192 + i) * 3;
    int cx = cell1d(p[0]);
    int cy = cell1d(p[1]);
    int cz = cell1d(p[2]);
    atomicAdd(&cnt[k * NCELLS + (cz * NC + cy) * NC + cx], 1u);
}

__global__ __launch_bounds__(1024) void grid_scan(unsigned int* __restrict__ cnt) {
    // One block per cloud: exclusive prefix sum over 32768 cells in
    // linear cell order (cloud-local offsets, start at 0).
    __shared__ unsigned int ssum[1024];
    int k = threadIdx.y + blockIdx.x;         // blockIdx.x = cloud
    k = blockIdx.x;
    int t = threadIdx.x;
    unsigned int base = (unsigned int)k * NCELLS + (unsigned int)t * 32;
    unsigned int c[32];
    unsigned int s = 0;
#pragma unroll
    for (int j = 0; j < 32; ++j) { c[j] = cnt[base + j]; s += c[j]; }
    ssum[t] = s;
    __syncthreads();
    for (int off = 1; off < 1024; off <<= 1) {
        unsigned int v = (t >= off) ? ssum[t - off] : 0u;
        __syncthreads();
        ssum[t] += v;
        __syncthreads();
    }
    unsigned int run = ssum[t] - s;           // exclusive prefix
#pragma unroll
    for (int j = 0; j < 32; ++j) { cnt[base + j] = run; run += c[j]; }
}

__global__ __launch_bounds__(256) void grid_scatter(const float* __restrict__ x,
                                                    const float* __restrict__ y,
                                                    unsigned int* __restrict__ cur,
                                                    v4f* __restrict__ P) {
#pragma clang fp contract(off)
    int g = blockIdx.x * 256 + threadIdx.x;   // 0..65535
    int k = g >> 13;
    int i = g & 8191;
    int n = k >> 1, w = k & 1;
    const float* src = w ? y : x;
    const float* p = src + (size_t)(n * 8192 + i) * 3;
    float a = p[0], b = p[1], c = p[2];
    int cx = cell1d(a);
    int cy = cell1d(b);
    int cz = cell1d(c);
    int cell = (cz * NC + cy) * NC + cx;
    unsigned int pos = atomicAdd(&cur[k * NCELLS + cell], 1u);
    v4f v;
    v.x = a; v.y = b; v.z = c; v.w = __uint_as_float((unsigned int)i);
    P[k * 8192 + (int)pos] = v;
    // After this kernel, cur[cell] = start[cell] + count[cell] =
    // start[cell+1] (linear order) -> end-pointer array for the search.
}

__global__ __launch_bounds__(256) void grid_search(const unsigned int* __restrict__ E,
                                                   const v4f* __restrict__ P,
                                                   float* __restrict__ out) {
#pragma clang fp contract(off)
    int g = blockIdx.x * 256 + threadIdx.x;   // sorted slot 0..65535
    int k = g >> 13;                          // query's cloud
    int n = k >> 1, w = k & 1;                // w==0: x->y (dir 0), w==1: y->x
    int tk = n * 2 + (w ^ 1);                 // target cloud

    v4f q = P[g];
    float qx = q.x, qy = q.y, qz = q.z;
    int qi = (int)__float_as_uint(q.w);       // query's original local idx
    float sp = ((qx * qx) + (qy * qy)) + (qz * qz);

    int cx = cell1d(qx), cy = cell1d(qy), cz = cell1d(qz);

    const unsigned int* tE = E + tk * NCELLS; // cloud-local end pointers
    const v4f* tP = P + tk * 8192;

    float bt = __builtin_inff();
    int bi = 0x7fffffff;

    for (int r = 0; r <= NC; ++r) {
        if (r >= 1) {
            // Explored box through ring r-1: cells [c-(r-1), c+(r-1)] per
            // axis -> real-space [GL0+(c-r+1)*GH, GL0+(c+r)*GH].
            float blx = GL0 + (float)(cx - r + 1) * GH;
            float bhx = GL0 + (float)(cx + r) * GH;
            float bly = GL0 + (float)(cy - r + 1) * GH;
            float bhy = GL0 + (float)(cy + r) * GH;
            float blz = GL0 + (float)(cz - r + 1) * GH;
            float bhz = GL0 + (float)(cz + r) * GH;
            float mf = fminf(fminf(fminf(qx - blx, bhx - qx),
                                   fminf(qy - bly, bhy - qy)),
                             fminf(qz - blz, bhz - qz));
            mf -= 1e-5f;                       // box-edge rounding margin
            if (mf > 0.0f && bt < mf * mf - 5e-5f) break;
        }
        int zlo = max(cz - r, 0), zhi = min(cz + r, NC - 1);
        for (int z = zlo; z <= zhi; ++z) {
            int adz = z - cz; adz = (adz < 0) ? -adz : adz;
            int ylo = max(cy - r, 0), yhi = min(cy + r, NC - 1);
            for (int yy = ylo; yy <= yhi; ++yy) {
                int ady = yy - cy; ady = (ady < 0) ? -ady : ady;
                // shell-only enumeration: if this z/y row is interior,
                // only xx = cx +- r belong to ring r.
                int step = (adz == r || ady == r) ? 1 : 2 * r;
                for (int xx = cx - r; xx <= cx + r; xx += step) {
                    if (xx < 0 || xx >= NC) continue;
                    int cell = (z * NC + yy) * NC + xx;
                    unsigned int s1 = tE[cell];
                    unsigned int s0 = cell ? tE[cell - 1] : 0u;
                    for (unsigned int kk = s0; kk < s1; ++kk) {
                        v4f t = tP[kk];
                        float tx = t.x, ty = t.y, tz = t.z;
                        int oi = (int)__float_as_uint(t.w);
                        float sq = ((tx * tx) + (ty * ty)) + (tz * tz);
                        float dot = ((qx * tx) + (qy * ty)) + (qz * tz);
                        float tt = fmaf(-2.0f, dot, sp + sq);
                        if (tt < bt || (tt == bt && oi < bi)) { bt = tt; bi = oi; }
                    }
                }
            }
        }
    }

    int o = n * 8192 + qi;
    out[w * 32768 + o]         = bt;          // cham_x at 0, cham_y at 32768
    out[65536 + w * 32768 + o] = (float)bi;   // idx_x at 65536, idx_y at 98304
}

extern "C" void kernel_launch(void* const* d_in, const int* in_sizes, int n_in,
                              void* d_out, int out_size, void* d_ws, size_t ws_size,
                              hipStream_t stream) {
    const float* x = (const float*)d_in[0];
    const float* y = (const float*)d_in[1];
    unsigned int* cnt = (unsigned int*)d_ws;
    v4f* P = (v4f*)((float*)d_ws + OFF_P);
    float* out = (float*)d_out;

    hipMemsetAsync(cnt, 0, 8 * NCELLS * sizeof(unsigned int), stream);
    grid_count<<<256, 256, 0, stream>>>(x, y, cnt);
    grid_scan<<<8, 1024, 0, stream>>>(cnt);
    grid_scatter<<<256, 256, 0, stream>>>(x, y, cnt, P);
    grid_search<<<256, 256, 0, stream>>>(cnt, P, out);
}

// Round 7
// 401.852 us; speedup vs baseline: 1.4415x; 1.4415x over previous
//
#include <hip/hip_runtime.h>

// Chamfer distance K=1 NN, both directions, via EXACT grid-pruned search.
// N=4, P1=P2=8192, D=3, fp32. Points ~ N(0,1)^3.
//
// Exactness argument (no approximation anywhere in the OUTPUT):
//  - Every candidate pair distance uses the bitwise reference formula
//    (fp contract off):  dot = ((qx*tx)+(qy*ty))+(qz*tz);
//                        tt  = fmaf(-2, dot, sp+sq)
//    with sp/sq = ((x*x)+(y*y))+(z*z).
//  - Selection is lexicographic min over (tt, orig_idx): identical to
//    numpy argmin first-occurrence semantics (smallest index on ties).
//  - Ring expansion stop: the unexplored target region is grid \ box
//    (box = cells explored through ring r-1). For each box face:
//      * face strictly inside the grid -> contributes (distance from the
//        query to that face plane);
//      * face at/past the grid edge -> contributes +inf (no cells, hence
//        no targets, beyond it).
//    mf = min(6 contributions) - 1e-5 (box-edge rounding margin). Break
//    when mf > 0 and best < mf^2 - 5e-5 (absolute slack covering
//    worst-case rounding of tt vs true d2; |coords|<=5.5 -> < 2.5e-5).
//    Unexplored true d2 >= mf^2, so unexplored tt > best strictly (ties
//    included). This is the round-6 fix: clamped outliers (|coord|>4.8)
//    and grid-edge queries previously never satisfied mf>0 and walked
//    the whole grid serially (the 526 us straggler tail).
//  - Scatter order within a cell is atomic-nondeterministic, but the
//    explored SET and the lexicographic min are order-independent ->
//    deterministic results across runs/replays.
//
// ws layout (32-bit slots, total 524288 = 2 MB):
//   [0      .. 262143]  u32 cnt[8 clouds][32768 cells]:
//                       counts (K1) -> exclusive starts (K2) ->
//                       cursors/end-pointers (K3/K4: E[c] = start[c+1])
//   [262144 .. 524287]  v4f P[65536]: sorted (x, y, z, idx_bits) AoS

typedef float v4f __attribute__((ext_vector_type(4)));

#define NC 32
#define NCELLS (NC * NC * NC)
#define GL0 -4.8f
#define GH 0.3f
#define GINVH (1.0f / 0.3f)

#define OFF_CNT 0
#define OFF_P   262144

__device__ __forceinline__ int cell1d(float v) {
#pragma clang fp contract(off)
    // (v - GL0) * GINVH : sub-then-mul, no fma contraction possible;
    // identical sequence in all kernels (K1/K3 consistency required).
    int c = (int)floorf((v - GL0) * GINVH);
    return min(max(c, 0), NC - 1);
}

__global__ __launch_bounds__(256) void grid_count(const float* __restrict__ x,
                                                  const float* __restrict__ y,
                                                  unsigned int* __restrict__ cnt) {
#pragma clang fp contract(off)
    int g = blockIdx.x * 256 + threadIdx.x;   // 0..65535
    int k = g >> 13;                          // cloud = batch*2 + w
    int i = g & 8191;
    int n = k >> 1, w = k & 1;
    const float* src = w ? y : x;
    const float* p = src + (size_t)(n * 8192 + i) * 3;
    int cx = cell1d(p[0]);
    int cy = cell1d(p[1]);
    int cz = cell1d(p[2]);
    atomicAdd(&cnt[k * NCELLS + (cz * NC + cy) * NC + cx], 1u);
}

__global__ __launch_bounds__(1024) void grid_scan(unsigned int* __restrict__ cnt) {
    // One block per cloud: exclusive prefix sum over 32768 cells in
    // linear cell order (cloud-local offsets, start at 0).
    __shared__ unsigned int ssum[1024];
    int k = blockIdx.x;
    int t = threadIdx.x;
    unsigned int base = (unsigned int)k * NCELLS + (unsigned int)t * 32;
    unsigned int c[32];
    unsigned int s = 0;
#pragma unroll
    for (int j = 0; j < 32; ++j) { c[j] = cnt[base + j]; s += c[j]; }
    ssum[t] = s;
    __syncthreads();
    for (int off = 1; off < 1024; off <<= 1) {
        unsigned int v = (t >= off) ? ssum[t - off] : 0u;
        __syncthreads();
        ssum[t] += v;
        __syncthreads();
    }
    unsigned int run = ssum[t] - s;           // exclusive prefix
#pragma unroll
    for (int j = 0; j < 32; ++j) { cnt[base + j] = run; run += c[j]; }
}

__global__ __launch_bounds__(256) void grid_scatter(const float* __restrict__ x,
                                                    const float* __restrict__ y,
                                                    unsigned int* __restrict__ cur,
                                                    v4f* __restrict__ P) {
#pragma clang fp contract(off)
    int g = blockIdx.x * 256 + threadIdx.x;   // 0..65535
    int k = g >> 13;
    int i = g & 8191;
    int n = k >> 1, w = k & 1;
    const float* src = w ? y : x;
    const float* p = src + (size_t)(n * 8192 + i) * 3;
    float a = p[0], b = p[1], c = p[2];
    int cx = cell1d(a);
    int cy = cell1d(b);
    int cz = cell1d(c);
    int cell = (cz * NC + cy) * NC + cx;
    unsigned int pos = atomicAdd(&cur[k * NCELLS + cell], 1u);
    v4f v;
    v.x = a; v.y = b; v.z = c; v.w = __uint_as_float((unsigned int)i);
    P[k * 8192 + (int)pos] = v;
    // After this kernel, cur[cell] = start[cell] + count[cell] =
    // start[cell+1] (linear order) -> end-pointer array for the search.
}

__global__ __launch_bounds__(256) void grid_search(const unsigned int* __restrict__ E,
                                                   const v4f* __restrict__ P,
                                                   float* __restrict__ out) {
#pragma clang fp contract(off)
    int g = blockIdx.x * 256 + threadIdx.x;   // sorted slot 0..65535
    int k = g >> 13;                          // query's cloud
    int n = k >> 1, w = k & 1;                // w==0: x->y (dir 0), w==1: y->x
    int tk = n * 2 + (w ^ 1);                 // target cloud

    v4f q = P[g];
    float qx = q.x, qy = q.y, qz = q.z;
    int qi = (int)__float_as_uint(q.w);       // query's original local idx
    float sp = ((qx * qx) + (qy * qy)) + (qz * qz);

    int cx = cell1d(qx), cy = cell1d(qy), cz = cell1d(qz);

    const unsigned int* tE = E + tk * NCELLS; // cloud-local end pointers
    const v4f* tP = P + tk * 8192;

    float bt = __builtin_inff();
    int bi = 0x7fffffff;

    // candidate scan of cells [s0,s1): exact reference numerics,
    // lexicographic (tt, idx) min; unrolled x2 for load ILP.
    auto scan = [&](unsigned int s0, unsigned int s1) {
#pragma clang fp contract(off)
        unsigned int kk = s0;
        for (; kk + 2 <= s1; kk += 2) {
            v4f t0 = tP[kk];
            v4f t1 = tP[kk + 1];
            float sq0 = ((t0.x * t0.x) + (t0.y * t0.y)) + (t0.z * t0.z);
            float dot0 = ((qx * t0.x) + (qy * t0.y)) + (qz * t0.z);
            float tt0 = fmaf(-2.0f, dot0, sp + sq0);
            int oi0 = (int)__float_as_uint(t0.w);
            if (tt0 < bt || (tt0 == bt && oi0 < bi)) { bt = tt0; bi = oi0; }
            float sq1 = ((t1.x * t1.x) + (t1.y * t1.y)) + (t1.z * t1.z);
            float dot1 = ((qx * t1.x) + (qy * t1.y)) + (qz * t1.z);
            float tt1 = fmaf(-2.0f, dot1, sp + sq1);
            int oi1 = (int)__float_as_uint(t1.w);
            if (tt1 < bt || (tt1 == bt && oi1 < bi)) { bt = tt1; bi = oi1; }
        }
        if (kk < s1) {
            v4f t0 = tP[kk];
            float sq0 = ((t0.x * t0.x) + (t0.y * t0.y)) + (t0.z * t0.z);
            float dot0 = ((qx * t0.x) + (qy * t0.y)) + (qz * t0.z);
            float tt0 = fmaf(-2.0f, dot0, sp + sq0);
            int oi0 = (int)__float_as_uint(t0.w);
            if (tt0 < bt || (tt0 == bt && oi0 < bi)) { bt = tt0; bi = oi0; }
        }
    };

    const float INF = __builtin_inff();
    for (int r = 0; r <= NC; ++r) {
        if (r >= 1) {
            // Explored box through ring r-1: cells [c-(r-1), c+(r-1)].
            // Per-face contribution to distance(query, grid \ box):
            // a face at/past the grid edge has NO unexplored cells beyond
            // it -> +inf (round-6 fix: outlier/edge queries now break).
            float mfx0 = (cx - r + 1 > 0)
                       ? qx - (GL0 + (float)(cx - r + 1) * GH) : INF;
            float mfx1 = (cx + r - 1 < NC - 1)
                       ? (GL0 + (float)(cx + r) * GH) - qx : INF;
            float mfy0 = (cy - r + 1 > 0)
                       ? qy - (GL0 + (float)(cy - r + 1) * GH) : INF;
            float mfy1 = (cy + r - 1 < NC - 1)
                       ? (GL0 + (float)(cy + r) * GH) - qy : INF;
            float mfz0 = (cz - r + 1 > 0)
                       ? qz - (GL0 + (float)(cz - r + 1) * GH) : INF;
            float mfz1 = (cz + r - 1 < NC - 1)
                       ? (GL0 + (float)(cz + r) * GH) - qz : INF;
            float mf = fminf(fminf(fminf(mfx0, mfx1), fminf(mfy0, mfy1)),
                             fminf(mfz0, mfz1));
            mf -= 1e-5f;                       // box-edge rounding margin
            // mf == +inf (box covers grid) -> breaks whenever bt finite.
            if (mf > 0.0f && bt < mf * mf - 5e-5f) break;
        }
        int zlo = max(cz - r, 0), zhi = min(cz + r, NC - 1);
        for (int z = zlo; z <= zhi; ++z) {
            int adz = z - cz; adz = (adz < 0) ? -adz : adz;
            int ylo = max(cy - r, 0), yhi = min(cy + r, NC - 1);
            for (int yy = ylo; yy <= yhi; ++yy) {
                int ady = yy - cy; ady = (ady < 0) ? -ady : ady;
                int rowbase = (z * NC + yy) * NC;
                if (adz == r || ady == r) {
                    // boundary row: contiguous [xlo..xhi]; carry s0->s1
                    // so each cell costs one E load.
                    int xlo = max(cx - r, 0), xhi = min(cx + r, NC - 1);
                    int c0 = rowbase + xlo;
                    unsigned int s0 = c0 ? tE[c0 - 1] : 0u;
                    for (int xx = xlo; xx <= xhi; ++xx) {
                        unsigned int s1 = tE[rowbase + xx];
                        if (s1 > s0) scan(s0, s1);
                        s0 = s1;
                    }
                } else {
                    // interior row: only xx = cx +- r are in ring r.
                    int xx = cx - r;
                    if (xx >= 0) {
                        int c = rowbase + xx;
                        unsigned int s1 = tE[c];
                        unsigned int s0 = c ? tE[c - 1] : 0u;
                        if (s1 > s0) scan(s0, s1);
                    }
                    xx = cx + r;
                    if (xx <= NC - 1) {
                        int c = rowbase + xx;
                        unsigned int s1 = tE[c];
                        unsigned int s0 = c ? tE[c - 1] : 0u;
                        if (s1 > s0) scan(s0, s1);
                    }
                }
            }
        }
    }

    int o = n * 8192 + qi;
    out[w * 32768 + o]         = bt;          // cham_x at 0, cham_y at 32768
    out[65536 + w * 32768 + o] = (float)bi;   // idx_x at 65536, idx_y at 98304
}

extern "C" void kernel_launch(void* const* d_in, const int* in_sizes, int n_in,
                              void* d_out, int out_size, void* d_ws, size_t ws_size,
                              hipStream_t stream) {
    const float* x = (const float*)d_in[0];
    const float* y = (const float*)d_in[1];
    unsigned int* cnt = (unsigned int*)d_ws;
    v4f* P = (v4f*)((float*)d_ws + OFF_P);
    float* out = (float*)d_out;

    hipMemsetAsync(cnt, 0, 8 * NCELLS * sizeof(unsigned int), stream);
    grid_count<<<256, 256, 0, stream>>>(x, y, cnt);
    grid_scan<<<8, 1024, 0, stream>>>(cnt);
    grid_scatter<<<256, 256, 0, stream>>>(x, y, cnt, P);
    grid_search<<<256, 256, 0, stream>>>(cnt, P, out);
}

// Round 8
// 159.529 us; speedup vs baseline: 3.6312x; 2.5190x over previous
//
#include <hip/hip_runtime.h>

// Chamfer distance K=1 NN, both directions: EXACT two-phase grid search.
// N=4, P1=P2=8192, D=3, fp32. Points ~ N(0,1)^3.
//
// Phase split (round-7 lesson: ring-walking has a latency-serial straggler
// tail on sparse queries; replace open-ended walk with fixed work):
//   phase-1 (grid_search): scan exactly the 3^3 cell box around the query.
//     Resolution test: for the explored box [x0,x1]x[y0,y1]x[z0,z1],
//     each face contributes distance(query, face plane) if the face is
//     strictly inside the grid, else +inf (no cells beyond it). mf =
//     min(6) - 1e-5 (face-coord rounding). Resolved iff mf > 0 and
//     bt < mf^2 - 2e-4 (slack covers worst-case |tt - true d2| rounding,
//     ~1e-4 for |coords|<=5.5; conservative = more fallback, never wrong).
//     Unresolved queries are appended to a list.
//   phase-2 (grid_fallback): one wave per listed query brute-forces ALL
//     8192 targets (coalesced, uniform cost) -> trivially exact, no skew.
// Both phases: candidate key = bitwise reference formula (contract off):
//     dot = ((qx*tx)+(qy*ty))+(qz*tz);  tt = fmaf(-2, dot, sp+sq),
//     sp/sq = ((x*x)+(y*y))+(z*z);
// selection = lexicographic min (tt, orig_idx)  == numpy argmin semantics.
// Scatter order inside a cell is atomic-nondeterministic but scanned SETS
// and lexicographic min are order-independent -> deterministic output.
//
// Dispatch-count diet: ~10 us/dispatch observed. count+scan+scatter+memset
// fused into ONE 8-block kernel (per-cloud 128 KiB LDS histogram).
//
// ws byte layout (<= 2 MB):
//   [0       .. 524287 ]  u16 E[8][32768]   cloud-local end pointers
//   [524288  .. 1572863]  v4f P[65536]      sorted (x,y,z,idx_bits)
//   [1572864 .. 1703935]  u16 list[65536]   unresolved query slots
//   [1703936 .. 1703939]  u32 listcnt
//   [1703940 .. 1704451]  u32 wsum[8][16]   bin-kernel scan scratch

typedef float v4f __attribute__((ext_vector_type(4)));

#define NC 32
#define NCELLS (NC * NC * NC)
#define GL0 -4.8f
#define GH 0.3f
#define GINVH (1.0f / 0.3f)
#define INFF __builtin_inff()

#define OFF_E    0
#define OFF_P    524288
#define OFF_LIST 1572864
#define OFF_CNT  1703936
#define OFF_WSUM 1703940

__device__ __forceinline__ int cell1d(float v) {
#pragma clang fp contract(off)
    // sub-then-mul: no fma contraction possible; identical sequence in
    // bin and search (cell-assignment consistency is correctness-critical).
    int c = (int)floorf((v - GL0) * GINVH);
    return min(max(c, 0), NC - 1);
}

// One block per cloud: LDS histogram -> exclusive scan -> scatter -> E.
__global__ __launch_bounds__(1024) void grid_bin(const float* __restrict__ x,
                                                 const float* __restrict__ y,
                                                 unsigned short* __restrict__ E,
                                                 v4f* __restrict__ P,
                                                 unsigned int* __restrict__ listcnt,
                                                 unsigned int* __restrict__ wsum) {
#pragma clang fp contract(off)
    __shared__ unsigned int cnt[NCELLS];         // 128 KiB
    int k = blockIdx.x;                          // cloud = batch*2 + w
    int t = threadIdx.x;
    int lane = t & 63;
    int wv = t >> 6;                             // wave 0..15
#pragma unroll
    for (int j = 0; j < NCELLS / 1024; ++j) cnt[t + j * 1024] = 0u;
    if (k == 0 && t == 0) *listcnt = 0u;

    int n = k >> 1, w = k & 1;
    const float* src = w ? y : x;
    float ax[8], ay[8], az[8]; int ci[8];
#pragma unroll
    for (int j = 0; j < 8; ++j) {
        int i = t + j * 1024;
        const float* p = src + (size_t)(n * 8192 + i) * 3;
        ax[j] = p[0]; ay[j] = p[1]; az[j] = p[2];
    }
    __syncthreads();                             // zeroing complete
#pragma unroll
    for (int j = 0; j < 8; ++j) {
        int cx = cell1d(ax[j]), cy = cell1d(ay[j]), cz = cell1d(az[j]);
        ci[j] = (cz * NC + cy) * NC + cx;
        atomicAdd(&cnt[ci[j]], 1u);
    }
    __syncthreads();

    // exclusive scan over 32768 cells: 32/thread + wave shfl + wave sums.
    unsigned int c[32]; unsigned int s = 0;
#pragma unroll
    for (int j = 0; j < 32; ++j) { c[j] = cnt[t * 32 + j]; s += c[j]; }
    unsigned int incl = s;
#pragma unroll
    for (int off = 1; off < 64; off <<= 1) {
        unsigned int v = (unsigned int)__shfl_up((int)incl, off, 64);
        if (lane >= off) incl += v;
    }
    if (lane == 63) wsum[k * 16 + wv] = incl;    // wave total
    __syncthreads();
    unsigned int base = 0;
    for (int ww = 0; ww < wv; ++ww) base += wsum[k * 16 + ww];
    unsigned int run = base + incl - s;          // thread-chunk exclusive base
#pragma unroll
    for (int j = 0; j < 32; ++j) {
        unsigned int tmp = c[j]; cnt[t * 32 + j] = run; run += tmp;
    }
    __syncthreads();

    // scatter (cnt = cursors); afterwards cnt[c] = end pointer E[c].
#pragma unroll
    for (int j = 0; j < 8; ++j) {
        unsigned int pos = atomicAdd(&cnt[ci[j]], 1u);
        v4f v;
        v.x = ax[j]; v.y = ay[j]; v.z = az[j];
        v.w = __uint_as_float((unsigned int)(t + j * 1024));
        P[k * 8192 + (int)pos] = v;
    }
    __syncthreads();
#pragma unroll
    for (int j = 0; j < NCELLS / 1024; ++j)
        E[k * NCELLS + t + j * 1024] = (unsigned short)cnt[t + j * 1024];
}

// Phase-1: fixed 3^3 box scan + exact resolution test.
__global__ __launch_bounds__(256) void grid_search(const unsigned short* __restrict__ E,
                                                   const v4f* __restrict__ P,
                                                   float* __restrict__ out,
                                                   unsigned short* __restrict__ list,
                                                   unsigned int* __restrict__ listcnt) {
#pragma clang fp contract(off)
    int g = blockIdx.x * 256 + threadIdx.x;      // sorted slot 0..65535
    int k = g >> 13;
    int n = k >> 1, w = k & 1;                   // w==0: x->y, w==1: y->x
    int tk = n * 2 + (w ^ 1);                    // target cloud

    v4f q = P[g];
    float qx = q.x, qy = q.y, qz = q.z;
    float sp = ((qx * qx) + (qy * qy)) + (qz * qz);
    int cx = cell1d(qx), cy = cell1d(qy), cz = cell1d(qz);

    const unsigned short* tE = E + tk * NCELLS;
    const v4f* tP = P + tk * 8192;

    int x0 = max(cx - 1, 0), x1 = min(cx + 1, NC - 1);
    int zz[3] = {max(cz - 1, 0), cz, min(cz + 1, NC - 1)};
    int yv[3] = {max(cy - 1, 0), cy, min(cy + 1, NC - 1)};
    // duplicate rows at grid edges are idempotent (lexicographic min;
    // strict compares never switch on an equal (tt, idx) re-encounter).

    // issue all 18 row-range loads up front (full MLP).
    unsigned int rs[9], re[9];
#pragma unroll
    for (int a = 0; a < 3; ++a)
#pragma unroll
        for (int bb = 0; bb < 3; ++bb) {
            int rb = (zz[a] * NC + yv[bb]) * NC;
            int c0 = rb + x0;
            rs[a * 3 + bb] = c0 ? (unsigned int)tE[c0 - 1] : 0u;  // flat prefix
            re[a * 3 + bb] = (unsigned int)tE[rb + x1];
        }

    float bt = INFF; int bi = 0x7fffffff;
#pragma unroll
    for (int rr = 0; rr < 9; ++rr) {
        unsigned int kk = rs[rr], s1 = re[rr];
        for (; kk + 2 <= s1; kk += 2) {
            v4f t0 = tP[kk];
            v4f t1 = tP[kk + 1];
            float sq0 = ((t0.x * t0.x) + (t0.y * t0.y)) + (t0.z * t0.z);
            float dt0 = ((qx * t0.x) + (qy * t0.y)) + (qz * t0.z);
            float tt0 = fmaf(-2.0f, dt0, sp + sq0);
            int oi0 = (int)__float_as_uint(t0.w);
            if (tt0 < bt || (tt0 == bt && oi0 < bi)) { bt = tt0; bi = oi0; }
            float sq1 = ((t1.x * t1.x) + (t1.y * t1.y)) + (t1.z * t1.z);
            float dt1 = ((qx * t1.x) + (qy * t1.y)) + (qz * t1.z);
            float tt1 = fmaf(-2.0f, dt1, sp + sq1);
            int oi1 = (int)__float_as_uint(t1.w);
            if (tt1 < bt || (tt1 == bt && oi1 < bi)) { bt = tt1; bi = oi1; }
        }
        if (kk < s1) {
            v4f t0 = tP[kk];
            float sq0 = ((t0.x * t0.x) + (t0.y * t0.y)) + (t0.z * t0.z);
            float dt0 = ((qx * t0.x) + (qy * t0.y)) + (qz * t0.z);
            float tt0 = fmaf(-2.0f, dt0, sp + sq0);
            int oi0 = (int)__float_as_uint(t0.w);
            if (tt0 < bt || (tt0 == bt && oi0 < bi)) { bt = tt0; bi = oi0; }
        }
    }

    // resolution test: faces at/past the grid edge -> +inf contribution.
    float mfx0 = (x0 > 0)      ? qx - (GL0 + (float)x0 * GH)       : INFF;
    float mfx1 = (x1 < NC - 1) ? (GL0 + (float)(x1 + 1) * GH) - qx : INFF;
    float mfy0 = (yv[0] > 0)      ? qy - (GL0 + (float)yv[0] * GH)       : INFF;
    float mfy1 = (yv[2] < NC - 1) ? (GL0 + (float)(yv[2] + 1) * GH) - qy : INFF;
    float mfz0 = (zz[0] > 0)      ? qz - (GL0 + (float)zz[0] * GH)       : INFF;
    float mfz1 = (zz[2] < NC - 1) ? (GL0 + (float)(zz[2] + 1) * GH) - qz : INFF;
    float mf = fminf(fminf(fminf(mfx0, mfx1), fminf(mfy0, mfy1)),
                     fminf(mfz0, mfz1)) - 1e-5f;

    if (mf > 0.0f && bt < mf * mf - 2e-4f) {
        int qi = (int)__float_as_uint(q.w);
        int o = n * 8192 + qi;
        out[w * 32768 + o]         = bt;
        out[65536 + w * 32768 + o] = (float)bi;
    } else {
        unsigned int li = atomicAdd(listcnt, 1u);
        list[li] = (unsigned short)g;
    }
}

// Phase-2: one wave per unresolved query, brute-force all 8192 targets.
__global__ __launch_bounds__(256) void grid_fallback(const unsigned short* __restrict__ list,
                                                     const unsigned int* __restrict__ listcnt,
                                                     const v4f* __restrict__ P,
                                                     float* __restrict__ out) {
#pragma clang fp contract(off)
    unsigned int cntv = *listcnt;
    int wid = blockIdx.x * 4 + (threadIdx.x >> 6);   // 0..2047
    int lane = threadIdx.x & 63;

    for (unsigned int li = (unsigned int)wid; li < cntv; li += 2048u) {
        int g = (int)list[li];
        int k = g >> 13;
        int n = k >> 1, w = k & 1;
        int tk = n * 2 + (w ^ 1);
        v4f q = P[g];
        float qx = q.x, qy = q.y, qz = q.z;
        float sp = ((qx * qx) + (qy * qy)) + (qz * qz);
        const v4f* tP = P + tk * 8192;

        float bt = INFF; int bi = 0x7fffffff;
#pragma unroll 4
        for (int it = 0; it < 128; ++it) {
            v4f tv = tP[it * 64 + lane];             // coalesced
            float sq = ((tv.x * tv.x) + (tv.y * tv.y)) + (tv.z * tv.z);
            float dt = ((qx * tv.x) + (qy * tv.y)) + (qz * tv.z);
            float tt = fmaf(-2.0f, dt, sp + sq);
            int oi = (int)__float_as_uint(tv.w);
            if (tt < bt || (tt == bt && oi < bi)) { bt = tt; bi = oi; }
        }
        // wave lexicographic (tt, idx) butterfly reduce
#pragma unroll
        for (int off = 32; off > 0; off >>= 1) {
            float ot = __shfl_xor(bt, off, 64);
            int   oo = __shfl_xor(bi, off, 64);
            if (ot < bt || (ot == bt && oo < bi)) { bt = ot; bi = oo; }
        }
        if (lane == 0) {
            int qi = (int)__float_as_uint(q.w);
            int o = n * 8192 + qi;
            out[w * 32768 + o]         = bt;
            out[65536 + w * 32768 + o] = (float)bi;
        }
    }
}

extern "C" void kernel_launch(void* const* d_in, const int* in_sizes, int n_in,
                              void* d_out, int out_size, void* d_ws, size_t ws_size,
                              hipStream_t stream) {
    const float* x = (const float*)d_in[0];
    const float* y = (const float*)d_in[1];
    char* wsb = (char*)d_ws;
    unsigned short* E    = (unsigned short*)(wsb + OFF_E);
    v4f*            P    = (v4f*)(wsb + OFF_P);
    unsigned short* list = (unsigned short*)(wsb + OFF_LIST);
    unsigned int* listcnt = (unsigned int*)(wsb + OFF_CNT);
    unsigned int* wsum    = (unsigned int*)(wsb + OFF_WSUM);
    float* out = (float*)d_out;

    grid_bin<<<8, 1024, 0, stream>>>(x, y, E, P, listcnt, wsum);
    grid_search<<<256, 256, 0, stream>>>(E, P, out, list, listcnt);
    grid_fallback<<<512, 256, 0, stream>>>(list, listcnt, P, out);
}

// Round 9
// 142.580 us; speedup vs baseline: 4.0629x; 1.1189x over previous
//
#include <hip/hip_runtime.h>

// Chamfer distance K=1 NN, both directions: EXACT two-phase grid search.
// N=4, P1=P2=8192, D=3, fp32. Points ~ N(0,1)^3.
//
// Phase-1 (grid_search, 8 LANES PER QUERY): scan exactly the 3^3 cell box
//   around the query; lane sub handles rows rr == sub (mod 8) of the 9
//   rows, then 3-step shfl_xor lexicographic (tt, idx) reduce.
//   Resolution test: for the explored box, each face contributes
//   distance(query, face plane) if strictly inside the grid, else +inf
//   (no cells beyond it). mf = min(6) - 1e-5. Resolved iff mf > 0 and
//   bt < mf^2 - 2e-4 (slack covers worst-case |tt - true d2| rounding,
//   ~1e-4 for |coords|<=5.5; conservative = more fallback, never wrong).
//   Unresolved queries -> list.
// Phase-2 (grid_fallback): one wave per listed query brute-forces ALL
//   8192 targets (coalesced, uniform) -> trivially exact, no skew.
// Both phases: candidate key = bitwise reference formula (contract off):
//   dot = ((qx*tx)+(qy*ty))+(qz*tz);  tt = fmaf(-2, dot, sp+sq),
//   sp/sq = ((x*x)+(y*y))+(z*z);
// selection = lexicographic min (tt, orig_idx) == numpy argmin semantics.
// Scatter order inside a cell is atomic-nondeterministic but scanned SETS
// and lexicographic min are order-independent -> deterministic output.
//
// Binning (round-8 lesson: the fused 8-block kernel ran on 8 CUs, ~50us):
// wide count/scan/scatter kernels. To fit 2 MiB, the two clouds of a
// batch PACK into one u32 histogram (w=0 low 16 bits, w=1 high 16):
// per-cloud totals <= 8192 so u32 adds never carry across halves ->
// count atomicAdd(+1 / +65536), a single u32 exclusive scan scans both
// halves at once, scatter's packed atomic cursor yields per-cloud slots,
// and after scatter cnt[n][c] holds BOTH clouds' end pointers.
//
// ws byte layout (1.63 MiB <= 2 MiB):
//   [0       .. 524287 ]  u32 cnt[4 batches][32768 cells] packed lo/hi
//   [524288  .. 524291 ]  u32 listcnt          (memset covers cnt+listcnt)
//   [528384  .. 1576959]  v4f P[65536]  sorted (x,y,z,idx_bits), 16B align
//   [1576960 .. 1708031]  u16 list[65536]  unresolved query slots

typedef float v4f __attribute__((ext_vector_type(4)));

#define NC 32
#define NCELLS (NC * NC * NC)
#define GL0 -4.8f
#define GH 0.3f
#define GINVH (1.0f / 0.3f)
#define INFF __builtin_inff()

#define OFF_CNT  0
#define OFF_LCNT 524288
#define OFF_P    528384
#define OFF_LIST 1576960

__device__ __forceinline__ int cell1d(float v) {
#pragma clang fp contract(off)
    // sub-then-mul: no fma contraction possible; identical sequence in
    // count/scatter/search (cell-assignment consistency is critical).
    int c = (int)floorf((v - GL0) * GINVH);
    return min(max(c, 0), NC - 1);
}

__global__ __launch_bounds__(256) void grid_count(const float* __restrict__ x,
                                                  const float* __restrict__ y,
                                                  unsigned int* __restrict__ cnt) {
#pragma clang fp contract(off)
    int g = blockIdx.x * 256 + threadIdx.x;   // 0..65535
    int k = g >> 13;                          // cloud = batch*2 + w
    int i = g & 8191;
    int n = k >> 1, w = k & 1;
    const float* src = w ? y : x;
    const float* p = src + (size_t)(n * 8192 + i) * 3;
    int cx = cell1d(p[0]);
    int cy = cell1d(p[1]);
    int cz = cell1d(p[2]);
    atomicAdd(&cnt[n * NCELLS + (cz * NC + cy) * NC + cx], w ? 65536u : 1u);
}

__global__ __launch_bounds__(1024) void grid_scan(unsigned int* __restrict__ cnt) {
    // One block per BATCH: exclusive prefix sum over 32768 packed cells.
    // lo/hi halves scan simultaneously (no cross-half carry: totals<=8192).
    __shared__ unsigned int ssum[1024];
    int n = blockIdx.x;
    int t = threadIdx.x;
    unsigned int base = (unsigned int)n * NCELLS + (unsigned int)t * 32;
    unsigned int c[32];
    unsigned int s = 0;
#pragma unroll
    for (int j = 0; j < 32; ++j) { c[j] = cnt[base + j]; s += c[j]; }
    ssum[t] = s;
    __syncthreads();
    for (int off = 1; off < 1024; off <<= 1) {
        unsigned int v = (t >= off) ? ssum[t - off] : 0u;
        __syncthreads();
        ssum[t] += v;
        __syncthreads();
    }
    unsigned int run = ssum[t] - s;           // exclusive prefix (packed)
#pragma unroll
    for (int j = 0; j < 32; ++j) { unsigned int tmp = c[j]; cnt[base + j] = run; run += tmp; }
}

__global__ __launch_bounds__(256) void grid_scatter(const float* __restrict__ x,
                                                    const float* __restrict__ y,
                                                    unsigned int* __restrict__ cur,
                                                    v4f* __restrict__ P) {
#pragma clang fp contract(off)
    int g = blockIdx.x * 256 + threadIdx.x;   // 0..65535
    int k = g >> 13;
    int i = g & 8191;
    int n = k >> 1, w = k & 1;
    const float* src = w ? y : x;
    const float* p = src + (size_t)(n * 8192 + i) * 3;
    float a = p[0], b = p[1], c = p[2];
    int cell = (cell1d(c) * NC + cell1d(b)) * NC + cell1d(a);
    unsigned int old = atomicAdd(&cur[n * NCELLS + cell], w ? 65536u : 1u);
    unsigned int pos = (old >> (w ? 16 : 0)) & 0xffffu;
    v4f v;
    v.x = a; v.y = b; v.z = c; v.w = __uint_as_float((unsigned int)i);
    P[k * 8192 + (int)pos] = v;
    // afterwards cur[n][c] = packed end pointers for both clouds of batch n
}

// Phase-1: 8 lanes per query; fixed 3^3 box scan + exact resolution test.
__global__ __launch_bounds__(256) void grid_search(const unsigned int* __restrict__ E,
                                                   const v4f* __restrict__ P,
                                                   float* __restrict__ out,
                                                   unsigned short* __restrict__ list,
                                                   unsigned int* __restrict__ listcnt) {
#pragma clang fp contract(off)
    int t = threadIdx.x;
    int sub = t & 7;                             // lane within 8-group
    int g = blockIdx.x * 32 + (t >> 3);          // sorted slot 0..65535
    int k = g >> 13;
    int n = k >> 1, w = k & 1;                   // w==0: x->y, w==1: y->x
    int tw = w ^ 1;                              // target cloud half
    int tsh = tw * 16;

    v4f q = P[g];
    float qx = q.x, qy = q.y, qz = q.z;
    float sp = ((qx * qx) + (qy * qy)) + (qz * qz);
    int cx = cell1d(qx), cy = cell1d(qy), cz = cell1d(qz);

    const unsigned int* tE = E + n * NCELLS;     // packed end pointers
    const v4f* tP = P + (n * 2 + tw) * 8192;

    int x0 = max(cx - 1, 0), x1 = min(cx + 1, NC - 1);
    int zz[3] = {max(cz - 1, 0), cz, min(cz + 1, NC - 1)};
    int yv[3] = {max(cy - 1, 0), cy, min(cy + 1, NC - 1)};
    // duplicate rows at grid edges are idempotent under the lexicographic
    // (tt, idx) min, even when scanned by different lanes.

    float bt = INFF; int bi = 0x7fffffff;

    // lane sub scans rows rr = sub and sub+8 (only sub==0 gets row 8).
#pragma unroll
    for (int pass = 0; pass < 2; ++pass) {
        int rr = sub + pass * 8;
        if (rr > 8) break;
        int rb = (zz[rr / 3] * NC + yv[rr % 3]) * NC;
        int c0 = rb + x0;
        unsigned int s0 = c0 ? ((tE[c0 - 1] >> tsh) & 0xffffu) : 0u;
        unsigned int s1 = (tE[rb + x1] >> tsh) & 0xffffu;
        unsigned int kk = s0;
        for (; kk + 2 <= s1; kk += 2) {
            v4f t0 = tP[kk];
            v4f t1 = tP[kk + 1];
            float sq0 = ((t0.x * t0.x) + (t0.y * t0.y)) + (t0.z * t0.z);
            float dt0 = ((qx * t0.x) + (qy * t0.y)) + (qz * t0.z);
            float tt0 = fmaf(-2.0f, dt0, sp + sq0);
            int oi0 = (int)__float_as_uint(t0.w);
            if (tt0 < bt || (tt0 == bt && oi0 < bi)) { bt = tt0; bi = oi0; }
            float sq1 = ((t1.x * t1.x) + (t1.y * t1.y)) + (t1.z * t1.z);
            float dt1 = ((qx * t1.x) + (qy * t1.y)) + (qz * t1.z);
            float tt1 = fmaf(-2.0f, dt1, sp + sq1);
            int oi1 = (int)__float_as_uint(t1.w);
            if (tt1 < bt || (tt1 == bt && oi1 < bi)) { bt = tt1; bi = oi1; }
        }
        if (kk < s1) {
            v4f t0 = tP[kk];
            float sq0 = ((t0.x * t0.x) + (t0.y * t0.y)) + (t0.z * t0.z);
            float dt0 = ((qx * t0.x) + (qy * t0.y)) + (qz * t0.z);
            float tt0 = fmaf(-2.0f, dt0, sp + sq0);
            int oi0 = (int)__float_as_uint(t0.w);
            if (tt0 < bt || (tt0 == bt && oi0 < bi)) { bt = tt0; bi = oi0; }
        }
    }

    // lexicographic (tt, idx) reduce across the 8-lane group.
#pragma unroll
    for (int off = 1; off < 8; off <<= 1) {
        float ot = __shfl_xor(bt, off, 64);
        int   oo = __shfl_xor(bi, off, 64);
        if (ot < bt || (ot == bt && oo < bi)) { bt = ot; bi = oo; }
    }

    if (sub == 0) {
        // resolution test: faces at/past the grid edge -> +inf.
        float mfx0 = (x0 > 0)      ? qx - (GL0 + (float)x0 * GH)       : INFF;
        float mfx1 = (x1 < NC - 1) ? (GL0 + (float)(x1 + 1) * GH) - qx : INFF;
        float mfy0 = (yv[0] > 0)      ? qy - (GL0 + (float)yv[0] * GH)       : INFF;
        float mfy1 = (yv[2] < NC - 1) ? (GL0 + (float)(yv[2] + 1) * GH) - qy : INFF;
        float mfz0 = (zz[0] > 0)      ? qz - (GL0 + (float)zz[0] * GH)       : INFF;
        float mfz1 = (zz[2] < NC - 1) ? (GL0 + (float)(zz[2] + 1) * GH) - qz : INFF;
        float mf = fminf(fminf(fminf(mfx0, mfx1), fminf(mfy0, mfy1)),
                         fminf(mfz0, mfz1)) - 1e-5f;
        if (mf > 0.0f && bt < mf * mf - 2e-4f) {
            int qi = (int)__float_as_uint(q.w);
            int o = n * 8192 + qi;
            out[w * 32768 + o]         = bt;
            out[65536 + w * 32768 + o] = (float)bi;
        } else {
            unsigned int li = atomicAdd(listcnt, 1u);
            list[li] = (unsigned short)g;
        }
    }
}

// Phase-2: one wave per unresolved query, brute-force all 8192 targets.
__global__ __launch_bounds__(256) void grid_fallback(const unsigned short* __restrict__ list,
                                                     const unsigned int* __restrict__ listcnt,
                                                     const v4f* __restrict__ P,
                                                     float* __restrict__ out) {
#pragma clang fp contract(off)
    unsigned int cntv = *listcnt;
    int wid = blockIdx.x * 4 + (threadIdx.x >> 6);   // 0..2047
    int lane = threadIdx.x & 63;

    for (unsigned int li = (unsigned int)wid; li < cntv; li += 2048u) {
        int g = (int)list[li];
        int k = g >> 13;
        int n = k >> 1, w = k & 1;
        int tk = n * 2 + (w ^ 1);
        v4f q = P[g];
        float qx = q.x, qy = q.y, qz = q.z;
        float sp = ((qx * qx) + (qy * qy)) + (qz * qz);
        const v4f* tP = P + tk * 8192;

        float bt = INFF; int bi = 0x7fffffff;
#pragma unroll 4
        for (int it = 0; it < 128; ++it) {
            v4f tv = tP[it * 64 + lane];             // coalesced
            float sq = ((tv.x * tv.x) + (tv.y * tv.y)) + (tv.z * tv.z);
            float dt = ((qx * tv.x) + (qy * tv.y)) + (qz * tv.z);
            float tt = fmaf(-2.0f, dt, sp + sq);
            int oi = (int)__float_as_uint(tv.w);
            if (tt < bt || (tt == bt && oi < bi)) { bt = tt; bi = oi; }
        }
#pragma unroll
        for (int off = 32; off > 0; off >>= 1) {
            float ot = __shfl_xor(bt, off, 64);
            int   oo = __shfl_xor(bi, off, 64);
            if (ot < bt || (ot == bt && oo < bi)) { bt = ot; bi = oo; }
        }
        if (lane == 0) {
            int qi = (int)__float_as_uint(q.w);
            int o = n * 8192 + qi;
            out[w * 32768 + o]         = bt;
            out[65536 + w * 32768 + o] = (float)bi;
        }
    }
}

extern "C" void kernel_launch(void* const* d_in, const int* in_sizes, int n_in,
                              void* d_out, int out_size, void* d_ws, size_t ws_size,
                              hipStream_t stream) {
    const float* x = (const float*)d_in[0];
    const float* y = (const float*)d_in[1];
    char* wsb = (char*)d_ws;
    unsigned int*   cnt     = (unsigned int*)(wsb + OFF_CNT);
    unsigned int*   listcnt = (unsigned int*)(wsb + OFF_LCNT);
    v4f*            P       = (v4f*)(wsb + OFF_P);
    unsigned short* list    = (unsigned short*)(wsb + OFF_LIST);
    float* out = (float*)d_out;

    hipMemsetAsync(wsb, 0, OFF_LCNT + 4, stream);     // cnt + listcnt
    grid_count<<<256, 256, 0, stream>>>(x, y, cnt);
    grid_scan<<<4, 1024, 0, stream>>>(cnt);
    grid_scatter<<<256, 256, 0, stream>>>(x, y, cnt, P);
    grid_search<<<2048, 256, 0, stream>>>(cnt, P, out, list, listcnt);
    grid_fallback<<<512, 256, 0, stream>>>(list, listcnt, P, out);
}

// Round 10
// 122.236 us; speedup vs baseline: 4.7391x; 1.1664x over previous
//
#include <hip/hip_runtime.h>

// Chamfer distance K=1 NN, both directions: EXACT two-phase grid search.
// N=4, P1=P2=8192, D=3, fp32. Points ~ N(0,1)^3.
//
// Phase-1 (grid_search, 16 LANES PER QUERY): scan exactly the 3^3 cell box
//   around the query; lane sub (<9) scans row sub (rows are contiguous in
//   P), 2-chain unroll-4 inner loop, then 4-step shfl_xor lexicographic
//   (tt, idx) reduce over the 16-lane group.
//   Resolution test: for the explored box, each face contributes
//   distance(query, face plane) if strictly inside the grid, else +inf
//   (no cells beyond it). mf = min(6) - 1e-5. Resolved iff mf > 0 and
//   bt < mf^2 - 2e-4 (slack covers worst-case |tt - true d2| rounding,
//   ~1e-4 for |coords|<=5.5; conservative = more fallback, never wrong).
//   Unresolved queries -> list.
// Phase-2 (grid_fallback): one wave per listed query brute-forces ALL
//   8192 targets with 4 INDEPENDENT lexicographic chains (round-9 lesson:
//   a single compare chain serialized the load stream at ~570 cyc/iter;
//   chains partition targets, merge = same lexicographic min -> exact).
// Both phases: candidate key = bitwise reference formula (contract off):
//   dot = ((qx*tx)+(qy*ty))+(qz*tz);  tt = fmaf(-2, dot, sp+sq),
//   sp/sq = ((x*x)+(y*y))+(z*z);
// selection = lexicographic min (tt, orig_idx) == numpy argmin semantics.
// Scatter order inside a cell is atomic-nondeterministic but scanned SETS
// and lexicographic min are order-independent -> deterministic output.
//
// Binning: wide count/scan/scatter; the two clouds of a batch pack into
// one u32 histogram (w=0 low 16 bits, w=1 high 16; totals <= 8192 so no
// cross-half carry) -> single scan serves both clouds.
//
// Overhead calibration (rounds 1/4/7/8): flat ~44 us harness overhead,
// ~independent of dispatch count -> keep simple wide kernels, optimize
// kernel time only.
//
// ws byte layout (1.63 MiB <= 2 MiB):
//   [0       .. 524287 ]  u32 cnt[4 batches][32768 cells] packed lo/hi
//   [524288  .. 524291 ]  u32 listcnt          (memset covers cnt+listcnt)
//   [528384  .. 1576959]  v4f P[65536]  sorted (x,y,z,idx_bits), 16B align
//   [1576960 .. 1708031]  u16 list[65536]  unresolved query slots

typedef float v4f __attribute__((ext_vector_type(4)));

#define NC 32
#define NCELLS (NC * NC * NC)
#define GL0 -4.8f
#define GH 0.3f
#define GINVH (1.0f / 0.3f)
#define INFF __builtin_inff()

#define OFF_CNT  0
#define OFF_LCNT 524288
#define OFF_P    528384
#define OFF_LIST 1576960

__device__ __forceinline__ int cell1d(float v) {
#pragma clang fp contract(off)
    // sub-then-mul: no fma contraction possible; identical sequence in
    // count/scatter/search (cell-assignment consistency is critical).
    int c = (int)floorf((v - GL0) * GINVH);
    return min(max(c, 0), NC - 1);
}

__global__ __launch_bounds__(256) void grid_count(const float* __restrict__ x,
                                                  const float* __restrict__ y,
                                                  unsigned int* __restrict__ cnt) {
#pragma clang fp contract(off)
    int g = blockIdx.x * 256 + threadIdx.x;   // 0..65535
    int k = g >> 13;                          // cloud = batch*2 + w
    int i = g & 8191;
    int n = k >> 1, w = k & 1;
    const float* src = w ? y : x;
    const float* p = src + (size_t)(n * 8192 + i) * 3;
    int cx = cell1d(p[0]);
    int cy = cell1d(p[1]);
    int cz = cell1d(p[2]);
    atomicAdd(&cnt[n * NCELLS + (cz * NC + cy) * NC + cx], w ? 65536u : 1u);
}

__global__ __launch_bounds__(1024) void grid_scan(unsigned int* __restrict__ cnt) {
    // One block per BATCH: exclusive prefix sum over 32768 packed cells.
    // lo/hi halves scan simultaneously (no cross-half carry: totals<=8192).
    __shared__ unsigned int ssum[1024];
    int n = blockIdx.x;
    int t = threadIdx.x;
    unsigned int base = (unsigned int)n * NCELLS + (unsigned int)t * 32;
    unsigned int c[32];
    unsigned int s = 0;
#pragma unroll
    for (int j = 0; j < 32; ++j) { c[j] = cnt[base + j]; s += c[j]; }
    ssum[t] = s;
    __syncthreads();
    for (int off = 1; off < 1024; off <<= 1) {
        unsigned int v = (t >= off) ? ssum[t - off] : 0u;
        __syncthreads();
        ssum[t] += v;
        __syncthreads();
    }
    unsigned int run = ssum[t] - s;           // exclusive prefix (packed)
#pragma unroll
    for (int j = 0; j < 32; ++j) { unsigned int tmp = c[j]; cnt[base + j] = run; run += tmp; }
}

__global__ __launch_bounds__(256) void grid_scatter(const float* __restrict__ x,
                                                    const float* __restrict__ y,
                                                    unsigned int* __restrict__ cur,
                                                    v4f* __restrict__ P) {
#pragma clang fp contract(off)
    int g = blockIdx.x * 256 + threadIdx.x;   // 0..65535
    int k = g >> 13;
    int i = g & 8191;
    int n = k >> 1, w = k & 1;
    const float* src = w ? y : x;
    const float* p = src + (size_t)(n * 8192 + i) * 3;
    float a = p[0], b = p[1], c = p[2];
    int cell = (cell1d(c) * NC + cell1d(b)) * NC + cell1d(a);
    unsigned int old = atomicAdd(&cur[n * NCELLS + cell], w ? 65536u : 1u);
    unsigned int pos = (old >> (w ? 16 : 0)) & 0xffffu;
    v4f v;
    v.x = a; v.y = b; v.z = c; v.w = __uint_as_float((unsigned int)i);
    P[k * 8192 + (int)pos] = v;
    // afterwards cur[n][c] = packed end pointers for both clouds of batch n
}

// Phase-1: 16 lanes per query; fixed 3^3 box scan + exact resolution test.
__global__ __launch_bounds__(256) void grid_search(const unsigned int* __restrict__ E,
                                                   const v4f* __restrict__ P,
                                                   float* __restrict__ out,
                                                   unsigned short* __restrict__ list,
                                                   unsigned int* __restrict__ listcnt) {
#pragma clang fp contract(off)
    int t = threadIdx.x;
    int sub = t & 15;                            // lane within 16-group
    int g = blockIdx.x * 16 + (t >> 4);          // sorted slot 0..65535
    int k = g >> 13;
    int n = k >> 1, w = k & 1;                   // w==0: x->y, w==1: y->x
    int tw = w ^ 1;                              // target cloud half
    int tsh = tw * 16;

    v4f q = P[g];
    float qx = q.x, qy = q.y, qz = q.z;
    float sp = ((qx * qx) + (qy * qy)) + (qz * qz);
    int cx = cell1d(qx), cy = cell1d(qy), cz = cell1d(qz);

    const unsigned int* tE = E + n * NCELLS;     // packed end pointers
    const v4f* tP = P + (n * 2 + tw) * 8192;

    int x0 = max(cx - 1, 0), x1 = min(cx + 1, NC - 1);
    int zz[3] = {max(cz - 1, 0), cz, min(cz + 1, NC - 1)};
    int yv[3] = {max(cy - 1, 0), cy, min(cy + 1, NC - 1)};
    // duplicate rows at grid edges are idempotent under the lexicographic
    // (tt, idx) min, even when scanned by different lanes.

    float btA = INFF, btB = INFF;
    int   biA = 0x7fffffff, biB = 0x7fffffff;

    if (sub < 9) {                               // one contiguous row/lane
        int rb = (zz[sub / 3] * NC + yv[sub % 3]) * NC;
        int c0 = rb + x0;
        unsigned int s0 = c0 ? ((tE[c0 - 1] >> tsh) & 0xffffu) : 0u;
        unsigned int s1 = (tE[rb + x1] >> tsh) & 0xffffu;
        unsigned int kk = s0;
        for (; kk + 4 <= s1; kk += 4) {          // 4 loads in flight, 2 chains
            v4f t0 = tP[kk];
            v4f t1 = tP[kk + 1];
            v4f t2 = tP[kk + 2];
            v4f t3 = tP[kk + 3];
            float sq0 = ((t0.x * t0.x) + (t0.y * t0.y)) + (t0.z * t0.z);
            float dt0 = ((qx * t0.x) + (qy * t0.y)) + (qz * t0.z);
            float tt0 = fmaf(-2.0f, dt0, sp + sq0);
            int oi0 = (int)__float_as_uint(t0.w);
            if (tt0 < btA || (tt0 == btA && oi0 < biA)) { btA = tt0; biA = oi0; }
            float sq1 = ((t1.x * t1.x) + (t1.y * t1.y)) + (t1.z * t1.z);
            float dt1 = ((qx * t1.x) + (qy * t1.y)) + (qz * t1.z);
            float tt1 = fmaf(-2.0f, dt1, sp + sq1);
            int oi1 = (int)__float_as_uint(t1.w);
            if (tt1 < btB || (tt1 == btB && oi1 < biB)) { btB = tt1; biB = oi1; }
            float sq2 = ((t2.x * t2.x) + (t2.y * t2.y)) + (t2.z * t2.z);
            float dt2 = ((qx * t2.x) + (qy * t2.y)) + (qz * t2.z);
            float tt2 = fmaf(-2.0f, dt2, sp + sq2);
            int oi2 = (int)__float_as_uint(t2.w);
            if (tt2 < btA || (tt2 == btA && oi2 < biA)) { btA = tt2; biA = oi2; }
            float sq3 = ((t3.x * t3.x) + (t3.y * t3.y)) + (t3.z * t3.z);
            float dt3 = ((qx * t3.x) + (qy * t3.y)) + (qz * t3.z);
            float tt3 = fmaf(-2.0f, dt3, sp + sq3);
            int oi3 = (int)__float_as_uint(t3.w);
            if (tt3 < btB || (tt3 == btB && oi3 < biB)) { btB = tt3; biB = oi3; }
        }
        for (; kk < s1; ++kk) {
            v4f t0 = tP[kk];
            float sq0 = ((t0.x * t0.x) + (t0.y * t0.y)) + (t0.z * t0.z);
            float dt0 = ((qx * t0.x) + (qy * t0.y)) + (qz * t0.z);
            float tt0 = fmaf(-2.0f, dt0, sp + sq0);
            int oi0 = (int)__float_as_uint(t0.w);
            if (tt0 < btA || (tt0 == btA && oi0 < biA)) { btA = tt0; biA = oi0; }
        }
    }
    // merge chains, then lexicographic reduce across the 16-lane group.
    float bt = btA; int bi = biA;
    if (btB < bt || (btB == bt && biB < bi)) { bt = btB; bi = biB; }
#pragma unroll
    for (int off = 1; off < 16; off <<= 1) {
        float ot = __shfl_xor(bt, off, 64);
        int   oo = __shfl_xor(bi, off, 64);
        if (ot < bt || (ot == bt && oo < bi)) { bt = ot; bi = oo; }
    }

    if (sub == 0) {
        // resolution test: faces at/past the grid edge -> +inf.
        float mfx0 = (x0 > 0)      ? qx - (GL0 + (float)x0 * GH)       : INFF;
        float mfx1 = (x1 < NC - 1) ? (GL0 + (float)(x1 + 1) * GH) - qx : INFF;
        float mfy0 = (yv[0] > 0)      ? qy - (GL0 + (float)yv[0] * GH)       : INFF;
        float mfy1 = (yv[2] < NC - 1) ? (GL0 + (float)(yv[2] + 1) * GH) - qy : INFF;
        float mfz0 = (zz[0] > 0)      ? qz - (GL0 + (float)zz[0] * GH)       : INFF;
        float mfz1 = (zz[2] < NC - 1) ? (GL0 + (float)(zz[2] + 1) * GH) - qz : INFF;
        float mf = fminf(fminf(fminf(mfx0, mfx1), fminf(mfy0, mfy1)),
                         fminf(mfz0, mfz1)) - 1e-5f;
        if (mf > 0.0f && bt < mf * mf - 2e-4f) {
            int qi = (int)__float_as_uint(q.w);
            int o = n * 8192 + qi;
            out[w * 32768 + o]         = bt;
            out[65536 + w * 32768 + o] = (float)bi;
        } else {
            unsigned int li = atomicAdd(listcnt, 1u);
            list[li] = (unsigned short)g;
        }
    }
}

// Phase-2: one wave per unresolved query; 4 independent chains for MLP.
__global__ __launch_bounds__(256) void grid_fallback(const unsigned short* __restrict__ list,
                                                     const unsigned int* __restrict__ listcnt,
                                                     const v4f* __restrict__ P,
                                                     float* __restrict__ out) {
#pragma clang fp contract(off)
    unsigned int cntv = *listcnt;
    int wid = blockIdx.x * 4 + (threadIdx.x >> 6);   // 0..2047
    int lane = threadIdx.x & 63;

    for (unsigned int li = (unsigned int)wid; li < cntv; li += 2048u) {
        int g = (int)list[li];
        int k = g >> 13;
        int n = k >> 1, w = k & 1;
        int tk = n * 2 + (w ^ 1);
        v4f q = P[g];
        float qx = q.x, qy = q.y, qz = q.z;
        float sp = ((qx * qx) + (qy * qy)) + (qz * qz);
        const v4f* tP = P + tk * 8192;

        float bt0 = INFF, bt1 = INFF, bt2 = INFF, bt3 = INFF;
        int bi0 = 0x7fffffff, bi1 = 0x7fffffff, bi2 = 0x7fffffff, bi3 = 0x7fffffff;
        for (int it = 0; it < 32; ++it) {            // 4 loads/iter, 4 chains
            v4f t0 = tP[(it * 4 + 0) * 64 + lane];   // coalesced
            v4f t1 = tP[(it * 4 + 1) * 64 + lane];
            v4f t2 = tP[(it * 4 + 2) * 64 + lane];
            v4f t3 = tP[(it * 4 + 3) * 64 + lane];
            float sq0 = ((t0.x * t0.x) + (t0.y * t0.y)) + (t0.z * t0.z);
            float dt0 = ((qx * t0.x) + (qy * t0.y)) + (qz * t0.z);
            float tt0 = fmaf(-2.0f, dt0, sp + sq0);
            int oi0 = (int)__float_as_uint(t0.w);
            if (tt0 < bt0 || (tt0 == bt0 && oi0 < bi0)) { bt0 = tt0; bi0 = oi0; }
            float sq1 = ((t1.x * t1.x) + (t1.y * t1.y)) + (t1.z * t1.z);
            float dt1 = ((qx * t1.x) + (qy * t1.y)) + (qz * t1.z);
            float tt1 = fmaf(-2.0f, dt1, sp + sq1);
            int oi1 = (int)__float_as_uint(t1.w);
            if (tt1 < bt1 || (tt1 == bt1 && oi1 < bi1)) { bt1 = tt1; bi1 = oi1; }
            float sq2 = ((t2.x * t2.x) + (t2.y * t2.y)) + (t2.z * t2.z);
            float dt2 = ((qx * t2.x) + (qy * t2.y)) + (qz * t2.z);
            float tt2 = fmaf(-2.0f, dt2, sp + sq2);
            int oi2 = (int)__float_as_uint(t2.w);
            if (tt2 < bt2 || (tt2 == bt2 && oi2 < bi2)) { bt2 = tt2; bi2 = oi2; }
            float sq3 = ((t3.x * t3.x) + (t3.y * t3.y)) + (t3.z * t3.z);
            float dt3 = ((qx * t3.x) + (qy * t3.y)) + (qz * t3.z);
            float tt3 = fmaf(-2.0f, dt3, sp + sq3);
            int oi3 = (int)__float_as_uint(t3.w);
            if (tt3 < bt3 || (tt3 == bt3 && oi3 < bi3)) { bt3 = tt3; bi3 = oi3; }
        }
        // merge chains (disjoint target subsets -> lexicographic min exact)
        float bt = bt0; int bi = bi0;
        if (bt1 < bt || (bt1 == bt && bi1 < bi)) { bt = bt1; bi = bi1; }
        if (bt2 < bt || (bt2 == bt && bi2 < bi)) { bt = bt2; bi = bi2; }
        if (bt3 < bt || (bt3 == bt && bi3 < bi)) { bt = bt3; bi = bi3; }
#pragma unroll
        for (int off = 32; off > 0; off >>= 1) {
            float ot = __shfl_xor(bt, off, 64);
            int   oo = __shfl_xor(bi, off, 64);
            if (ot < bt || (ot == bt && oo < bi)) { bt = ot; bi = oo; }
        }
        if (lane == 0) {
            int qi = (int)__float_as_uint(q.w);
            int o = n * 8192 + qi;
            out[w * 32768 + o]         = bt;
            out[65536 + w * 32768 + o] = (float)bi;
        }
    }
}

extern "C" void kernel_launch(void* const* d_in, const int* in_sizes, int n_in,
                              void* d_out, int out_size, void* d_ws, size_t ws_size,
                              hipStream_t stream) {
    const float* x = (const float*)d_in[0];
    const float* y = (const float*)d_in[1];
    char* wsb = (char*)d_ws;
    unsigned int*   cnt     = (unsigned int*)(wsb + OFF_CNT);
    unsigned int*   listcnt = (unsigned int*)(wsb + OFF_LCNT);
    v4f*            P       = (v4f*)(wsb + OFF_P);
    unsigned short* list    = (unsigned short*)(wsb + OFF_LIST);
    float* out = (float*)d_out;

    hipMemsetAsync(wsb, 0, OFF_LCNT + 4, stream);     // cnt + listcnt
    grid_count<<<256, 256, 0, stream>>>(x, y, cnt);
    grid_scan<<<4, 1024, 0, stream>>>(cnt);
    grid_scatter<<<256, 256, 0, stream>>>(x, y, cnt, P);
    grid_search<<<4096, 256, 0, stream>>>(cnt, P, out, list, listcnt);
    grid_fallback<<<512, 256, 0, stream>>>(list, listcnt, P, out);
}